// Round 8
// baseline (300.256 us; speedup 1.0000x reference)
//
#include <hip/hip_runtime.h>

#define HW    9216          // h*w
#define CK    392           // 256 + 136
#define NVIS  2359296       // 256*9216 — visual/landmark boundary in flat concat
#define KP    672           // packed split-K: 392(hi·hi) + 136(hi·lo) + 136(lo·hi) + 8 pad
#define NKT   21            // KP/32
#define NRB   144           // 9216/64 row-blocks for colsum partials
#define MAXN  3584          // cap on padded selected-column count (nsel ~3072±45)
#define NB_N  28            // MAXN/128
#define PREF_BLOCKS 2352    // 21 * 112 (kt × 32-col windows)
#define PCOL_BLOCKS 144     // 9216/64
#define PSRC_BLOCKS 3024    // 9216*84/256

typedef __bf16 bf16_t;
typedef __bf16 bf16x8 __attribute__((ext_vector_type(8)));
typedef __bf16 bf16x4v __attribute__((ext_vector_type(4)));
typedef unsigned short ushort8v __attribute__((ext_vector_type(8)));
typedef float  f32x4  __attribute__((ext_vector_type(4)));

typedef __attribute__((address_space(1))) void void_g;
typedef __attribute__((address_space(3))) void void_l;

static __device__ __forceinline__ void gload16(const void* g, void* l) {
  __builtin_amdgcn_global_load_lds((const void_g*)g, (void_l*)l, 16, 0, 0);
}

// ---------- fused prep: prep_ref (0..2351) + prep_cols (2352..2495) + prep_src (2496..5519) ----------
__global__ __launch_bounds__(256) void fused_prep(
    const float* __restrict__ feat_src, const float* __restrict__ lm_src,
    const float* __restrict__ fr, const float* __restrict__ lm_ref,
    const int* __restrict__ ms, const int* __restrict__ mr,
    const float* __restrict__ w1, const float* __restrict__ b1,
    const float* __restrict__ w2, const float* __restrict__ b2,
    bf16_t* __restrict__ Sp, bf16_t* __restrict__ Rp,
    float* __restrict__ wbs, float* __restrict__ wgs, int* __restrict__ cnt)
{
  __shared__ float r1[4][64], r2[4][64];
  __shared__ int sb[4], st[4];
  __shared__ int qlist[32];
  __shared__ bf16_t tile[32][33];
  int bid = blockIdx.x, t = threadIdx.x;
  int lane = t & 63, wid = t >> 6;

  if (bid < PREF_BLOCKS) {
    // ---- prep_ref: R'' [n128][672] gathered+transposed; own rank-window compaction ----
    int qt = bid / NKT, kt = bid - qt * NKT;
    int n0 = qt * 32;
    if (t < 32) qlist[t] = -1;
    // pass 1: per-thread match count over blocked q-range [t*36, t*36+36)
    int c = 0;
    #pragma unroll
    for (int i = 0; i < 36; ++i) {
      int q = t * 36 + i;
      c += (ms[q] == mr[q]) ? 1 : 0;
    }
    int pref = c;
    #pragma unroll
    for (int d = 1; d < 64; d <<= 1) {
      int v = __shfl_up(pref, d);
      if (lane >= d) pref += v;
    }
    if (lane == 63) { sb[wid] = pref; }
    __syncthreads();
    int wbase = 0;
    for (int wv = 0; wv < wid; ++wv) wbase += sb[wv];
    int rank = wbase + pref - c;            // exclusive prefix in q-order
    int nsel = sb[0] + sb[1] + sb[2] + sb[3];
    int n128 = (nsel + 127) & ~127;
    // pass 2: write q's whose rank falls in [n0, n0+32)
    #pragma unroll
    for (int i = 0; i < 36; ++i) {
      int q = t * 36 + i;
      if (ms[q] == mr[q]) {
        if (rank >= n0 && rank < n0 + 32) qlist[rank - n0] = q;
        ++rank;
      }
    }
    __syncthreads();
    if (n0 >= n128) return;                 // block-uniform
    // gather + transpose (K-map: [0,392) hi; [392,528) LO; [528,664) HI; pad)
    int x = t & 31, y = t >> 5;
    int q = qlist[x];
    #pragma unroll
    for (int ry = 0; ry < 4; ++ry) {
      int kl = y + ry * 8;
      int k = kt * 32 + kl;
      int j = -1; bool lo = false;
      if (k < 392)      j = k;
      else if (k < 528) { j = k - 136; lo = true; }
      else if (k < 664) j = k - 272;
      bf16_t v = (bf16_t)0.f;
      if (j >= 0 && q >= 0) {
        int idx = j * HW + q;
        float xv = (idx < NVIS) ? 0.01f * fr[idx] : lm_ref[idx - NVIS];
        bf16_t h = (bf16_t)xv;
        v = lo ? (bf16_t)(xv - (float)h) : h;
      }
      tile[kl][x] = v;
    }
    __syncthreads();
    #pragma unroll
    for (int ry = 0; ry < 4; ++ry) {
      int ql = y + ry * 8;
      int k = kt * 32 + x;
      Rp[(long)(n0 + ql) * KP + k] = tile[x][ql];
    }
  } else if (bid < PREF_BLOCKS + PCOL_BLOCKS) {
    // ---- prep_cols: beta/gama for 64 q's + global-rank compacted wbs/wgs ----
    int b = bid - PREF_BLOCKS;
    int qi = t & 63, cg = t >> 6;
    int q0 = b * 64;
    float a1 = 0.f, a2 = 0.f;
    #pragma unroll 4
    for (int c = cg * 64; c < cg * 64 + 64; ++c) {
      float v = fr[(long)c * HW + q0 + qi];
      a1 += v * w1[c]; a2 += v * w2[c];
    }
    r1[cg][qi] = a1; r2[cg][qi] = a2;
    int cb = 0, ct = 0;
    for (int q = t; q < HW; q += 256) {
      bool f = (ms[q] == mr[q]);
      ct += f ? 1 : 0;
      cb += (f && q < q0) ? 1 : 0;
    }
    #pragma unroll
    for (int d = 1; d < 64; d <<= 1) {
      cb += __shfl_xor(cb, d);
      ct += __shfl_xor(ct, d);
    }
    if (lane == 0) { sb[wid] = cb; st[wid] = ct; }
    __syncthreads();
    int base = sb[0] + sb[1] + sb[2] + sb[3];
    if (t == 0 && b == 0) cnt[0] = st[0] + st[1] + st[2] + st[3];
    if (wid == 0) {
      int q = q0 + lane;
      bool flag = (ms[q] == mr[q]);
      unsigned long long mk = __ballot(flag);
      int pos = __popcll(mk & ((1ull << lane) - 1ull));
      if (flag) {
        int idx = base + pos;
        wbs[idx] = r1[0][lane] + r1[1][lane] + r1[2][lane] + r1[3][lane] + b1[0];
        wgs[idx] = r2[0][lane] + r2[1][lane] + r2[2][lane] + r2[3][lane] + b2[0];
      }
    }
  } else {
    // ---- prep_src: S' [9216][672] bf16, split-K packed, bf16x8 chunks ----
    int tid = (bid - PREF_BLOCKS - PCOL_BLOCKS) * 256 + t;  // 9216*84 chunks
    int i = tid / 84, kc = tid - i * 84;
    int ko = kc * 8;
    int j0 = 0; bool lo = false, zero = false;
    if (kc < 49)       j0 = ko;               // hi, j in [0,392)
    else if (kc < 66)  j0 = ko - 136;         // hi dup, j in [256,392)
    else if (kc < 83) { j0 = ko - 272; lo = true; }  // lo, j in [256,392)
    else               zero = true;
    bf16x8 pk = {};
    if (!zero) {
      int idx0 = i * CK + j0;                 // 8-aligned; never straddles NVIS
      const float* src = (idx0 < NVIS) ? (feat_src + idx0) : (lm_src + (idx0 - NVIS));
      float sc = (idx0 < NVIS) ? 0.01f : 1.f;
      float4 v0 = *reinterpret_cast<const float4*>(src);
      float4 v1 = *reinterpret_cast<const float4*>(src + 4);
      float x[8] = {v0.x, v0.y, v0.z, v0.w, v1.x, v1.y, v1.z, v1.w};
      #pragma unroll
      for (int e = 0; e < 8; ++e) {
        float xv = sc * x[e];
        bf16_t h = (bf16_t)xv;
        pk[e] = lo ? (bf16_t)(xv - (float)h) : h;
      }
    }
    *reinterpret_cast<bf16x8*>(Sp + (long)tid * 8) = pk;
  }
}

// ---------- single GEMM pass: E = exp(S@R) bf16 (n-packed cols) + colsum partials ----------
__global__ __launch_bounds__(256, 2) void gemm_e(
    const bf16_t* __restrict__ Sp, const bf16_t* __restrict__ Rp,
    const int* __restrict__ cnt, bf16_t* __restrict__ E, float* __restrict__ pd)
{
  const int bm = blockIdx.x, bn = blockIdx.y;
  if (bn * 128 >= ((cnt[0] + 127) & ~127)) return;
  __shared__ __align__(16) bf16_t As[128 * 32];
  __shared__ __align__(16) bf16_t Bs[128 * 32];
  const int t = threadIdx.x, w = t >> 6, lane = t & 63;
  const int wr = w >> 1, wc = w & 1;  // 2x2 waves, each owns 64x64
  f32x4 acc[4][4] = {};

  const int chs = ((lane & 3) ^ ((lane >> 3) & 3)) * 8;   // swizzled staging chunk
  const bf16_t* sA = Sp + (long)(bm * 128 + w * 32 + (lane >> 2)) * KP + chs;
  const bf16_t* sB = Rp + (long)(bn * 128 + w * 32 + (lane >> 2)) * KP + chs;
  bf16_t* lA = As + w * 1024;
  bf16_t* lB = Bs + w * 1024;
  const int sub = lane >> 4, r16 = lane & 15;
  const int swz = (sub ^ ((r16 >> 1) & 3)) * 8;            // swizzled read slot
  const int aoff = (wr * 64 + r16) * 32 + swz;
  const int boff = (wc * 64 + r16) * 32 + swz;

  for (int kt = 0; kt < NKT; ++kt) {
    gload16(sA, lA);
    gload16(sA + 16 * KP, lA + 512);
    gload16(sB, lB);
    gload16(sB + 16 * KP, lB + 512);
    sA += 32; sB += 32;
    __syncthreads();
    bf16x8 a[4], b[4];
    #pragma unroll
    for (int m = 0; m < 4; ++m)
      a[m] = *reinterpret_cast<const bf16x8*>(As + aoff + m * 512);
    #pragma unroll
    for (int n = 0; n < 4; ++n)
      b[n] = *reinterpret_cast<const bf16x8*>(Bs + boff + n * 512);
    #pragma unroll
    for (int m = 0; m < 4; ++m)
      #pragma unroll
      for (int n = 0; n < 4; ++n)
        acc[m][n] = __builtin_amdgcn_mfma_f32_16x16x32_bf16(a[m], b[n], acc[m][n], 0, 0, 0);
    __syncthreads();
  }

  // exp in place (no max-shift: |A| ≲ 70 → safe in f32/bf16)
  #pragma unroll
  for (int m = 0; m < 4; ++m)
    #pragma unroll
    for (int n = 0; n < 4; ++n)
      #pragma unroll
      for (int r = 0; r < 4; ++r)
        acc[m][n][r] = __expf(acc[m][n][r]);

  const int C = bn * 128 + wc * 64;
  {
    const int rb = bm * 2 + wr;
    float s[4];
    #pragma unroll
    for (int n = 0; n < 4; ++n) {
      float v = 0.f;
      #pragma unroll
      for (int m = 0; m < 4; ++m)
        #pragma unroll
        for (int r = 0; r < 4; ++r) v += acc[m][n][r];
      v += __shfl_xor(v, 16);
      v += __shfl_xor(v, 32);
      s[n] = v;
    }
    if (sub == 0) {
      f32x4 sv = {s[0], s[1], s[2], s[3]};
      *reinterpret_cast<f32x4*>(pd + (long)rb * MAXN + C + r16 * 4) = sv;
    }
  }
  // E store, n-packed column layout: stored col = C + c16*4 + n (orig col = C + n*16 + c16)
  bf16_t* Eb = E + (long)(bm * 128 + wr * 64 + sub * 4) * MAXN + C + r16 * 4;
  #pragma unroll
  for (int m = 0; m < 4; ++m)
    #pragma unroll
    for (int r = 0; r < 4; ++r) {
      bf16x4v pk;
      #pragma unroll
      for (int n = 0; n < 4; ++n) pk[n] = (bf16_t)acc[m][n][r];
      *reinterpret_cast<bf16x4v*>(Eb + (long)(m * 16 + r) * MAXN) = pk;
    }
}

// ---------- u[p] = M·{beta,gama}[orig(p)] / D[p], coalesced reduce ----------
__global__ __launch_bounds__(256) void make_u(
    const float* __restrict__ pd, const float* __restrict__ wbs,
    const float* __restrict__ wgs, const int* __restrict__ cnt,
    float* __restrict__ ub, float* __restrict__ ug)
{
  __shared__ float sD[4][64];
  int t = threadIdx.x, c = t & 63, g = t >> 6;
  int p = blockIdx.x * 64 + c;
  float D = 0.f;
  for (int rb = g * 36; rb < g * 36 + 36; ++rb)
    D += pd[(long)rb * MAXN + p];
  sD[g][c] = D;
  __syncthreads();
  if (g == 0) {
    int nsel = cnt[0];
    int n128 = (nsel + 127) & ~127;
    float Dt = sD[0][c] + sD[1][c] + sD[2][c] + sD[3][c];
    float vb = 0.f, vg = 0.f;
    if (p < n128) {
      int orig = (p & ~63) + (p & 3) * 16 + ((p >> 2) & 15);  // packed -> compacted idx
      if (orig < nsel) {
        float inv = 1.f / Dt;
        vb = wbs[orig] * inv;
        vg = wgs[orig] * inv;
      }
    }
    ub[p] = vb;
    ug[p] = vg;
  }
}

// ---------- matvec + finalize fused: 16 rows/block (576 blocks), u hoisted per chunk ----------
__global__ __launch_bounds__(256) void matvec_fin(
    const bf16_t* __restrict__ E, const float* __restrict__ ub,
    const float* __restrict__ ug, const int* __restrict__ cnt,
    const float* __restrict__ fs, float* __restrict__ out)
{
  __shared__ float bhs[16], ghs[16];
  int t = threadIdx.x, lane = t & 63, wv = t >> 6;
  int n128 = (cnt[0] + 127) & ~127;
  int R0 = blockIdx.x * 16;
  const bf16_t* Ew = E + (long)(R0 + wv * 4) * MAXN;
  float ab[4] = {}, ag[4] = {};
  for (int base = 0; base < n128; base += 512) {
    int c0 = base + lane * 8;
    if (c0 < n128) {                       // n128 % 128 == 0 → whole 8-chunk valid
      float4 u0a = *reinterpret_cast<const float4*>(ub + c0);
      float4 u0b = *reinterpret_cast<const float4*>(ub + c0 + 4);
      float4 u1a = *reinterpret_cast<const float4*>(ug + c0);
      float4 u1b = *reinterpret_cast<const float4*>(ug + c0 + 4);
      float u0[8] = {u0a.x, u0a.y, u0a.z, u0a.w, u0b.x, u0b.y, u0b.z, u0b.w};
      float u1[8] = {u1a.x, u1a.y, u1a.z, u1a.w, u1b.x, u1b.y, u1b.z, u1b.w};
      #pragma unroll
      for (int rr = 0; rr < 4; ++rr) {
        ushort8v e = *reinterpret_cast<const ushort8v*>(Ew + (long)rr * MAXN + c0);
        #pragma unroll
        for (int j = 0; j < 8; ++j) {
          float ev = __uint_as_float(((unsigned)e[j]) << 16);
          ab[rr] += ev * u0[j];
          ag[rr] += ev * u1[j];
        }
      }
    }
  }
  #pragma unroll
  for (int rr = 0; rr < 4; ++rr) {
    #pragma unroll
    for (int d = 1; d < 64; d <<= 1) {
      ab[rr] += __shfl_xor(ab[rr], d);
      ag[rr] += __shfl_xor(ag[rr], d);
    }
    if (lane == 0) { bhs[wv * 4 + rr] = ab[rr]; ghs[wv * 4 + rr] = ag[rr]; }
  }
  __syncthreads();
  // out[c, R0+p] = gh*fs + bh for all 256 channels; 16 pixels × 16 channel-groups
  int p = t & 15, cg = t >> 4;
  int P = R0 + p;
  float bv = bhs[p], gv = ghs[p];
  #pragma unroll 4
  for (int c = cg; c < 256; c += 16)
    out[(long)c * HW + P] = gv * fs[(long)c * HW + P] + bv;
}

extern "C" void kernel_launch(void* const* d_in, const int* in_sizes, int n_in,
                              void* d_out, int out_size, void* d_ws, size_t ws_size,
                              hipStream_t stream) {
  const float* feat_src = (const float*)d_in[0];
  const float* feat_ref = (const float*)d_in[1];
  const float* lm_src   = (const float*)d_in[2];
  const float* lm_ref   = (const float*)d_in[3];
  const int*   mask_src = (const int*)d_in[4];
  const int*   mask_ref = (const int*)d_in[5];
  const float* w1 = (const float*)d_in[6];
  const float* b1 = (const float*)d_in[7];
  const float* w2 = (const float*)d_in[8];
  const float* b2 = (const float*)d_in[9];
  float* out = (float*)d_out;

  char* ws = (char*)d_ws;
  bf16_t* Sp   = (bf16_t*)(ws);              // 9216*672*2   = 12,386,304
  bf16_t* Rp   = (bf16_t*)(ws + 12386304);   // 3584*672*2   =  4,816,896
  bf16_t* E    = (bf16_t*)(ws + 17203200);   // 9216*3584*2  = 66,060,288
  float* pd    = (float*)(ws + 83263488);    // 144*3584*4   =  2,064,384
  float* wb    = (float*)(ws + 85327872);    // 14,336 each below
  float* wg    = (float*)(ws + 85342208);
  float* ub    = (float*)(ws + 85356544);
  float* ug    = (float*)(ws + 85370880);
  int*   cnt   = (int*)  (ws + 85385216);    // total ~85.4 MB

  fused_prep<<<PREF_BLOCKS + PCOL_BLOCKS + PSRC_BLOCKS, 256, 0, stream>>>(
      feat_src, lm_src, feat_ref, lm_ref, mask_src, mask_ref, w1, b1, w2, b2,
      Sp, Rp, wb, wg, cnt);
  gemm_e<<<dim3(72, NB_N), 256, 0, stream>>>(Sp, Rp, cnt, E, pd);
  make_u<<<MAXN / 64, 256, 0, stream>>>(pd, wb, wg, cnt, ub, ug);
  matvec_fin<<<HW / 16, 256, 0, stream>>>(E, ub, ug, cnt, feat_src, out);
}

// Round 9
// 174.751 us; speedup vs baseline: 1.7182x; 1.7182x over previous
//
#include <hip/hip_runtime.h>

#define HW    9216          // h*w
#define CK    392           // 256 + 136
#define NVIS  2359296       // 256*9216 — visual/landmark boundary in flat concat
#define KP    672           // packed split-K: 392(hi·hi) + 136(hi·lo) + 136(lo·hi) + 8 pad
#define NKT   21            // KP/32
#define NKT_SHORT 13        // rows < 6016: corrections provably negligible (S all 0.01-scale)
#define BM_SPLIT 47         // bm < 47 → rows ≤ 6015 → short-K path
#define NRB   144           // 9216/64 row-blocks for colsum partials
#define MAXN  3584          // cap on padded selected-column count (nsel ~3072±45)
#define NB_N  28            // MAXN/128
#define PSRC_BLOCKS 3024    // 9216*84/256

typedef __bf16 bf16_t;
typedef __bf16 bf16x8 __attribute__((ext_vector_type(8)));
typedef __bf16 bf16x4v __attribute__((ext_vector_type(4)));
typedef unsigned short ushort8v __attribute__((ext_vector_type(8)));
typedef float  f32x4  __attribute__((ext_vector_type(4)));

typedef __attribute__((address_space(1))) void void_g;
typedef __attribute__((address_space(3))) void void_l;

static __device__ __forceinline__ void gload16(const void* g, void* l) {
  __builtin_amdgcn_global_load_lds((const void_g*)g, (void_l*)l, 16, 0, 0);
}

// ---------- fused: prep_src (blocks 0..3023) + prep_cols (blocks 3024..3167) ----------
// prep_cols: beta/gama for 64 q's + deterministic global-rank compaction (no atomics).
__global__ __launch_bounds__(256) void fused_prep(
    const float* __restrict__ feat_src, const float* __restrict__ lm_src,
    const float* __restrict__ fr, const int* __restrict__ ms,
    const int* __restrict__ mr, const float* __restrict__ w1,
    const float* __restrict__ b1, const float* __restrict__ w2,
    const float* __restrict__ b2,
    bf16_t* __restrict__ Sp, int* __restrict__ sel,
    float* __restrict__ wbs, float* __restrict__ wgs, int* __restrict__ cnt)
{
  __shared__ float r1[4][64], r2[4][64];
  __shared__ int sb[4], st[4];
  int bid = blockIdx.x, t = threadIdx.x;

  if (bid < PSRC_BLOCKS) {
    // ---- S' [9216][672] bf16, split-K packed, bf16x8 chunks ----
    int tid = bid * 256 + t;                  // over 9216 * 84 chunks
    int i = tid / 84, kc = tid - i * 84;
    int ko = kc * 8;
    int j0 = 0; bool lo = false, zero = false;
    if (kc < 49)       j0 = ko;               // hi, j in [0,392)
    else if (kc < 66)  j0 = ko - 136;         // hi dup, j in [256,392)
    else if (kc < 83) { j0 = ko - 272; lo = true; }  // lo, j in [256,392)
    else               zero = true;
    bf16x8 pk = {};
    if (!zero) {
      int idx0 = i * CK + j0;                 // 8-aligned; never straddles NVIS
      const float* src = (idx0 < NVIS) ? (feat_src + idx0) : (lm_src + (idx0 - NVIS));
      float sc = (idx0 < NVIS) ? 0.01f : 1.f;
      float4 v0 = *reinterpret_cast<const float4*>(src);
      float4 v1 = *reinterpret_cast<const float4*>(src + 4);
      float x[8] = {v0.x, v0.y, v0.z, v0.w, v1.x, v1.y, v1.z, v1.w};
      #pragma unroll
      for (int e = 0; e < 8; ++e) {
        float xv = sc * x[e];
        bf16_t h = (bf16_t)xv;
        pk[e] = lo ? (bf16_t)(xv - (float)h) : h;
      }
    }
    *reinterpret_cast<bf16x8*>(Sp + (long)tid * 8) = pk;
  } else {
    // ---- prep_cols for q range [64b, 64b+64) ----
    int b = bid - PSRC_BLOCKS;
    int qi = t & 63, cg = t >> 6, lane = t & 63, wid = t >> 6;
    int q0 = b * 64;
    // (a) beta/gama partials (4 channel-groups)
    float a1 = 0.f, a2 = 0.f;
    #pragma unroll 4
    for (int c = cg * 64; c < cg * 64 + 64; ++c) {
      float v = fr[(long)c * HW + q0 + qi];
      a1 += v * w1[c]; a2 += v * w2[c];
    }
    r1[cg][qi] = a1; r2[cg][qi] = a2;
    // (b) global rank: matches below q0, and total
    int cb = 0, ct = 0;
    for (int q = t; q < HW; q += 256) {
      bool f = (ms[q] == mr[q]);
      ct += f ? 1 : 0;
      cb += (f && q < q0) ? 1 : 0;
    }
    #pragma unroll
    for (int d = 1; d < 64; d <<= 1) {
      cb += __shfl_xor(cb, d);
      ct += __shfl_xor(ct, d);
    }
    if (lane == 0) { sb[wid] = cb; st[wid] = ct; }
    __syncthreads();
    int base = sb[0] + sb[1] + sb[2] + sb[3];
    if (t == 0 && b == 0) cnt[0] = st[0] + st[1] + st[2] + st[3];
    // (c) compact this block's 64 q's (wave 0)
    if (wid == 0) {
      int q = q0 + lane;
      bool flag = (ms[q] == mr[q]);
      unsigned long long mk = __ballot(flag);
      int pos = __popcll(mk & ((1ull << lane) - 1ull));
      if (flag) {
        int idx = base + pos;
        sel[idx] = q;
        wbs[idx] = r1[0][lane] + r1[1][lane] + r1[2][lane] + r1[3][lane] + b1[0];
        wgs[idx] = r2[0][lane] + r2[1][lane] + r2[2][lane] + r2[3][lane] + b2[0];
      }
    }
  }
}

// ---------- prep: R'' [n128][672] bf16 = gathered+transposed ref panel ----------
// K-map: [0,392) hi ; [392,528) LO (pairs S-hi) ; [528,664) HI (pairs S-lo)
__global__ __launch_bounds__(256) void prep_ref(
    const float* __restrict__ feat_ref, const float* __restrict__ lm_ref,
    const int* __restrict__ sel, const int* __restrict__ cnt,
    bf16_t* __restrict__ Rp)
{
  int nsel = cnt[0];
  int n128 = (nsel + 127) & ~127;
  int qt = blockIdx.y;
  if (qt * 32 >= n128) return;
  __shared__ bf16_t tile[32][33];
  int x = threadIdx.x & 31, y = threadIdx.x >> 5;
  int kt = blockIdx.x;
  int n = qt * 32 + x;
  int q = (n < nsel) ? sel[n] : -1;
  #pragma unroll
  for (int ry = 0; ry < 4; ++ry) {
    int kl = y + ry * 8;
    int k = kt * 32 + kl;
    int j = -1; bool lo = false;
    if (k < 392)      j = k;
    else if (k < 528) { j = k - 136; lo = true; }
    else if (k < 664) j = k - 272;
    bf16_t v = (bf16_t)0.f;
    if (j >= 0 && q >= 0) {
      int idx = j * HW + q;
      float xv = (idx < NVIS) ? 0.01f * feat_ref[idx] : lm_ref[idx - NVIS];
      bf16_t h = (bf16_t)xv;
      v = lo ? (bf16_t)(xv - (float)h) : h;
    }
    tile[kl][x] = v;
  }
  __syncthreads();
  #pragma unroll
  for (int ry = 0; ry < 4; ++ry) {
    int ql = y + ry * 8;
    int k = kt * 32 + x;
    Rp[(long)(qt * 32 + ql) * KP + k] = tile[x][ql];
  }
}

// ---------- single GEMM pass: E = exp(S@R) bf16 (n-packed cols) + colsum partials ----------
// Row-split K: bm < 47 (rows <= 6015, all S entries 0.01-scale) run 13 K-tiles —
// dropped correction terms are ~8e-4 in A. bm >= 47 runs full 21 (identical to R7).
__global__ __launch_bounds__(256, 2) void gemm_e(
    const bf16_t* __restrict__ Sp, const bf16_t* __restrict__ Rp,
    const int* __restrict__ cnt, bf16_t* __restrict__ E, float* __restrict__ pd)
{
  const int bm = blockIdx.x, bn = blockIdx.y;
  if (bn * 128 >= ((cnt[0] + 127) & ~127)) return;
  __shared__ __align__(16) bf16_t As[128 * 32];
  __shared__ __align__(16) bf16_t Bs[128 * 32];
  const int t = threadIdx.x, w = t >> 6, lane = t & 63;
  const int wr = w >> 1, wc = w & 1;  // 2x2 waves, each owns 64x64
  const int nkt = (bm < BM_SPLIT) ? NKT_SHORT : NKT;
  f32x4 acc[4][4] = {};

  const int chs = ((lane & 3) ^ ((lane >> 3) & 3)) * 8;   // swizzled staging chunk
  const bf16_t* sA = Sp + (long)(bm * 128 + w * 32 + (lane >> 2)) * KP + chs;
  const bf16_t* sB = Rp + (long)(bn * 128 + w * 32 + (lane >> 2)) * KP + chs;
  bf16_t* lA = As + w * 1024;
  bf16_t* lB = Bs + w * 1024;
  const int sub = lane >> 4, r16 = lane & 15;
  const int swz = (sub ^ ((r16 >> 1) & 3)) * 8;            // swizzled read slot
  const int aoff = (wr * 64 + r16) * 32 + swz;
  const int boff = (wc * 64 + r16) * 32 + swz;

  for (int kt = 0; kt < nkt; ++kt) {
    gload16(sA, lA);
    gload16(sA + 16 * KP, lA + 512);
    gload16(sB, lB);
    gload16(sB + 16 * KP, lB + 512);
    sA += 32; sB += 32;
    __syncthreads();
    bf16x8 a[4], b[4];
    #pragma unroll
    for (int m = 0; m < 4; ++m)
      a[m] = *reinterpret_cast<const bf16x8*>(As + aoff + m * 512);
    #pragma unroll
    for (int n = 0; n < 4; ++n)
      b[n] = *reinterpret_cast<const bf16x8*>(Bs + boff + n * 512);
    #pragma unroll
    for (int m = 0; m < 4; ++m)
      #pragma unroll
      for (int n = 0; n < 4; ++n)
        acc[m][n] = __builtin_amdgcn_mfma_f32_16x16x32_bf16(a[m], b[n], acc[m][n], 0, 0, 0);
    __syncthreads();
  }

  // exp in place (no max-shift: |A| ≲ 70 → safe in f32/bf16)
  #pragma unroll
  for (int m = 0; m < 4; ++m)
    #pragma unroll
    for (int n = 0; n < 4; ++n)
      #pragma unroll
      for (int r = 0; r < 4; ++r)
        acc[m][n][r] = __expf(acc[m][n][r]);

  const int C = bn * 128 + wc * 64;
  {
    const int rb = bm * 2 + wr;
    float s[4];
    #pragma unroll
    for (int n = 0; n < 4; ++n) {
      float v = 0.f;
      #pragma unroll
      for (int m = 0; m < 4; ++m)
        #pragma unroll
        for (int r = 0; r < 4; ++r) v += acc[m][n][r];
      v += __shfl_xor(v, 16);
      v += __shfl_xor(v, 32);
      s[n] = v;
    }
    if (sub == 0) {
      f32x4 sv = {s[0], s[1], s[2], s[3]};
      *reinterpret_cast<f32x4*>(pd + (long)rb * MAXN + C + r16 * 4) = sv;
    }
  }
  // E store, n-packed column layout: stored col = C + c16*4 + n (orig col = C + n*16 + c16)
  bf16_t* Eb = E + (long)(bm * 128 + wr * 64 + sub * 4) * MAXN + C + r16 * 4;
  #pragma unroll
  for (int m = 0; m < 4; ++m)
    #pragma unroll
    for (int r = 0; r < 4; ++r) {
      bf16x4v pk;
      #pragma unroll
      for (int n = 0; n < 4; ++n) pk[n] = (bf16_t)acc[m][n][r];
      *reinterpret_cast<bf16x4v*>(Eb + (long)(m * 16 + r) * MAXN) = pk;
    }
}

// ---------- u[p] = M·{beta,gama}[orig(p)] / D[p], coalesced reduce ----------
__global__ __launch_bounds__(256) void make_u(
    const float* __restrict__ pd, const float* __restrict__ wbs,
    const float* __restrict__ wgs, const int* __restrict__ cnt,
    float* __restrict__ ub, float* __restrict__ ug)
{
  __shared__ float sD[4][64];
  int t = threadIdx.x, c = t & 63, g = t >> 6;
  int p = blockIdx.x * 64 + c;
  float D = 0.f;
  for (int rb = g * 36; rb < g * 36 + 36; ++rb)
    D += pd[(long)rb * MAXN + p];
  sD[g][c] = D;
  __syncthreads();
  if (g == 0) {
    int nsel = cnt[0];
    int n128 = (nsel + 127) & ~127;
    float Dt = sD[0][c] + sD[1][c] + sD[2][c] + sD[3][c];
    float vb = 0.f, vg = 0.f;
    if (p < n128) {
      int orig = (p & ~63) + (p & 3) * 16 + ((p >> 2) & 15);  // packed -> compacted idx
      if (orig < nsel) {
        float inv = 1.f / Dt;
        vb = wbs[orig] * inv;
        vg = wgs[orig] * inv;
      }
    }
    ub[p] = vb;
    ug[p] = vg;
  }
}

// ---------- matvec + finalize fused: 16 rows/block (576 blocks), u hoisted per chunk ----------
__global__ __launch_bounds__(256) void matvec_fin(
    const bf16_t* __restrict__ E, const float* __restrict__ ub,
    const float* __restrict__ ug, const int* __restrict__ cnt,
    const float* __restrict__ fs, float* __restrict__ out)
{
  __shared__ float bhs[16], ghs[16];
  int t = threadIdx.x, lane = t & 63, wv = t >> 6;
  int n128 = (cnt[0] + 127) & ~127;
  int R0 = blockIdx.x * 16;
  const bf16_t* Ew = E + (long)(R0 + wv * 4) * MAXN;
  float ab[4] = {}, ag[4] = {};
  for (int base = 0; base < n128; base += 512) {
    int c0 = base + lane * 8;
    if (c0 < n128) {                       // n128 % 128 == 0 → whole 8-chunk valid
      float4 u0a = *reinterpret_cast<const float4*>(ub + c0);
      float4 u0b = *reinterpret_cast<const float4*>(ub + c0 + 4);
      float4 u1a = *reinterpret_cast<const float4*>(ug + c0);
      float4 u1b = *reinterpret_cast<const float4*>(ug + c0 + 4);
      float u0[8] = {u0a.x, u0a.y, u0a.z, u0a.w, u0b.x, u0b.y, u0b.z, u0b.w};
      float u1[8] = {u1a.x, u1a.y, u1a.z, u1a.w, u1b.x, u1b.y, u1b.z, u1b.w};
      #pragma unroll
      for (int rr = 0; rr < 4; ++rr) {
        ushort8v e = *reinterpret_cast<const ushort8v*>(Ew + (long)rr * MAXN + c0);
        #pragma unroll
        for (int j = 0; j < 8; ++j) {
          float ev = __uint_as_float(((unsigned)e[j]) << 16);
          ab[rr] += ev * u0[j];
          ag[rr] += ev * u1[j];
        }
      }
    }
  }
  #pragma unroll
  for (int rr = 0; rr < 4; ++rr) {
    #pragma unroll
    for (int d = 1; d < 64; d <<= 1) {
      ab[rr] += __shfl_xor(ab[rr], d);
      ag[rr] += __shfl_xor(ag[rr], d);
    }
    if (lane == 0) { bhs[wv * 4 + rr] = ab[rr]; ghs[wv * 4 + rr] = ag[rr]; }
  }
  __syncthreads();
  // out[c, R0+p] = gh*fs + bh for all 256 channels; 16 pixels × 16 channel-groups
  int p = t & 15, cg = t >> 4;
  int P = R0 + p;
  float bv = bhs[p], gv = ghs[p];
  #pragma unroll 4
  for (int c = cg; c < 256; c += 16)
    out[(long)c * HW + P] = gv * fs[(long)c * HW + P] + bv;
}

extern "C" void kernel_launch(void* const* d_in, const int* in_sizes, int n_in,
                              void* d_out, int out_size, void* d_ws, size_t ws_size,
                              hipStream_t stream) {
  const float* feat_src = (const float*)d_in[0];
  const float* feat_ref = (const float*)d_in[1];
  const float* lm_src   = (const float*)d_in[2];
  const float* lm_ref   = (const float*)d_in[3];
  const int*   mask_src = (const int*)d_in[4];
  const int*   mask_ref = (const int*)d_in[5];
  const float* w1 = (const float*)d_in[6];
  const float* b1 = (const float*)d_in[7];
  const float* w2 = (const float*)d_in[8];
  const float* b2 = (const float*)d_in[9];
  float* out = (float*)d_out;

  char* ws = (char*)d_ws;
  bf16_t* Sp   = (bf16_t*)(ws);              // 9216*672*2   = 12,386,304
  bf16_t* Rp   = (bf16_t*)(ws + 12386304);   // 3584*672*2   =  4,816,896
  bf16_t* E    = (bf16_t*)(ws + 17203200);   // 9216*3584*2  = 66,060,288
  float* pd    = (float*)(ws + 83263488);    // 144*3584*4   =  2,064,384
  float* wb    = (float*)(ws + 85327872);    // 14,336 each below
  float* wg    = (float*)(ws + 85342208);
  float* ub    = (float*)(ws + 85356544);
  float* ug    = (float*)(ws + 85370880);
  int*   sel   = (int*)  (ws + 85385216);
  int*   cnt   = (int*)  (ws + 85399552);    // total ~85.4 MB

  fused_prep<<<PSRC_BLOCKS + HW / 64, 256, 0, stream>>>(
      feat_src, lm_src, feat_ref, mask_src, mask_ref, w1, b1, w2, b2,
      Sp, sel, wb, wg, cnt);
  prep_ref<<<dim3(NKT, MAXN / 32), 256, 0, stream>>>(feat_ref, lm_ref, sel, cnt, Rp);
  gemm_e<<<dim3(72, NB_N), 256, 0, stream>>>(Sp, Rp, cnt, E, pd);
  make_u<<<MAXN / 64, 256, 0, stream>>>(pd, wb, wg, cnt, ub, ug);
  matvec_fin<<<HW / 16, 256, 0, stream>>>(E, ub, ug, cnt, feat_src, out);
}